// Round 9
// baseline (482.436 us; speedup 1.0000x reference)
//
#include <hip/hip_runtime.h>
#include <math.h>

#define Bq 2
#define Lq 2048
#define DIMq 768
#define NHq 12
#define HDq 64
#define LOG2E 1.44269504f

typedef __attribute__((ext_vector_type(8))) short short8;
typedef __attribute__((ext_vector_type(4))) short short4v;
typedef __attribute__((ext_vector_type(4))) float float4v;
typedef __attribute__((ext_vector_type(4))) int int4v;

typedef __attribute__((address_space(3))) unsigned int as3_u32;
typedef __attribute__((address_space(1))) unsigned int as1_u32;

static __device__ __forceinline__ short f2bf(float f) {
    union { float f; unsigned u; } v; v.f = f;
    unsigned r = (v.u + 0x7FFF + ((v.u >> 16) & 1)) >> 16;   // RNE
    return (short)r;
}

// 16x16x16 bf16 MFMA: builtin if present, else raw ISA (cdna4_isa.md §10)
#if __has_builtin(__builtin_amdgcn_mfma_f32_16x16x16bf16_1k)
static __device__ __forceinline__ float4v mfma16(short4v a, short4v b, float4v c) {
    return __builtin_amdgcn_mfma_f32_16x16x16bf16_1k(a, b, c, 0, 0, 0);
}
#else
static __device__ __forceinline__ float4v mfma16(short4v a, short4v b, float4v c) {
    asm volatile("s_nop 1\n\tv_mfma_f32_16x16x16_bf16 %0, %1, %2, %0"
                 : "+v"(c) : "v"(a), "v"(b));
    return c;
}
#endif

// async global->LDS, 16B per lane (wave-uniform LDS base + lane*16)
static __device__ __forceinline__ void gld_lds16(const short* g, short* l) {
    __builtin_amdgcn_global_load_lds((const as1_u32*)g, (as3_u32*)l, 16, 0, 0);
}

// ---------------------------------------------------------------------------
// fp32 -> bf16 conversion for x and the four weight matrices.
// ---------------------------------------------------------------------------
__global__ __launch_bounds__(256)
void to_bf16(const float* __restrict__ x,  const float* __restrict__ wq,
             const float* __restrict__ wk, const float* __restrict__ wv,
             const float* __restrict__ wo,
             short* __restrict__ xb, short* __restrict__ wqb,
             short* __restrict__ wkb, short* __restrict__ wvb,
             short* __restrict__ wob)
{
    int blk = blockIdx.x;
    const float* s; short* d; int off;
    if      (blk <  768) { s = x;  d = xb;  off = blk * 1024; }
    else if (blk <  912) { s = wq; d = wqb; off = (blk -  768) * 1024; }
    else if (blk < 1056) { s = wk; d = wkb; off = (blk -  912) * 1024; }
    else if (blk < 1200) { s = wv; d = wvb; off = (blk - 1056) * 1024; }
    else                 { s = wo; d = wob; off = (blk - 1200) * 1024; }
    const float4* s4 = (const float4*)s;
    short4v* d4 = (short4v*)d;
#pragma unroll
    for (int i = 0; i < 4; ++i) {
        int idx = off + threadIdx.x + i * 256;
        float4 v = s4[idx];
        short4v o;
        o[0] = f2bf(v.x); o[1] = f2bf(v.y); o[2] = f2bf(v.z); o[3] = f2bf(v.w);
        d4[idx] = o;
    }
}

// ---------------------------------------------------------------------------
// bf16 MFMA GEMM, templated tile 128xBN (BN = 128 or 64), BK=64 (round-8).
// ---------------------------------------------------------------------------
template<int BN>
__global__ __launch_bounds__(256, 3)
void gemm_bf16(const short* __restrict__ A,
               const short* __restrict__ W0, const short* __restrict__ W1,
               const short* __restrict__ W2,
               short* __restrict__ D0, short* __restrict__ D1,
               short* __restrict__ D2, float* __restrict__ DF, int mode)
{
    constexpr int NT = BN / 32;            // frags per wave in n
    const int z = blockIdx.z;
    const short* W = (z == 0) ? W0 : ((z == 1) ? W1 : W2);
    short* DH = (z == 0) ? D0 : ((z == 1) ? D1 : D2);

    __shared__ __align__(16) short As[128][64];   // linear: global_load_lds dst
    __shared__ __align__(16) short Ws[BN][64];

    const int tid  = threadIdx.x;
    const int wave = tid >> 6;
    const int lane = tid & 63;
    const int col  = lane & 15;
    const int quad = lane >> 4;
    const int wr = wave >> 1, wc = wave & 1;
    const int m0 = blockIdx.y * 128, n0 = blockIdx.x * BN;

    float4v acc[4][NT];
#pragma unroll
    for (int mt = 0; mt < 4; ++mt)
#pragma unroll
        for (int nt = 0; nt < NT; ++nt) acc[mt][nt] = (float4v){0.f, 0.f, 0.f, 0.f};

    const short* Ab = A + (size_t)m0 * DIMq;
    const short* Wb = W + (size_t)n0 * DIMq;

    for (int k0 = 0; k0 < DIMq; k0 += 64) {
        __syncthreads();                       // readers done with LDS
#pragma unroll
        for (int i = 0; i < 4; ++i) {
            int g = i * 256 + tid;
            int row = g >> 3, ch = g & 7;
            gld_lds16(Ab + (size_t)row * DIMq + k0 + ch * 8, (short*)As + g * 8);
        }
#pragma unroll
        for (int i = 0; i < BN / 32; ++i) {
            int g = i * 256 + tid;
            int row = g >> 3, ch = g & 7;
            gld_lds16(Wb + (size_t)row * DIMq + k0 + ch * 8, (short*)Ws + g * 8);
        }
        __syncthreads();                       // (compiler drains vmcnt here)
#pragma unroll
        for (int kk = 0; kk < 2; ++kk) {
            short8 a[4], bfr[NT];
#pragma unroll
            for (int mt = 0; mt < 4; ++mt)
                a[mt] = *(const short8*)&As[wr * 64 + mt * 16 + col][kk * 32 + quad * 8];
#pragma unroll
            for (int nt = 0; nt < NT; ++nt)
                bfr[nt] = *(const short8*)&Ws[wc * (BN / 2) + nt * 16 + col][kk * 32 + quad * 8];
#pragma unroll
            for (int mt = 0; mt < 4; ++mt)
#pragma unroll
                for (int nt = 0; nt < NT; ++nt)
                    acc[mt][nt] = __builtin_amdgcn_mfma_f32_16x16x32_bf16(
                        a[mt], bfr[nt], acc[mt][nt], 0, 0, 0);
        }
    }

#pragma unroll
    for (int mt = 0; mt < 4; ++mt)
#pragma unroll
    for (int reg = 0; reg < 4; ++reg) {
        int m = m0 + wr * 64 + mt * 16 + quad * 4 + reg;
#pragma unroll
        for (int nt = 0; nt < NT; ++nt) {
            int n = n0 + wc * (BN / 2) + nt * 16 + col;
            if (mode == 1) {
                int b = m >> 11, l = m & 2047, h = n >> 6, c = n & 63;
                DH[(((size_t)(b * NHq + h)) * Lq + l) * HDq + c] = f2bf(acc[mt][nt][reg]);
            } else {
                DF[(size_t)m * DIMq + n] = acc[mt][nt][reg];
            }
        }
    }
}

// ---------------------------------------------------------------------------
// V transpose: [B][NH][L][HD] -> [B][NH][HD][L], once.
// ---------------------------------------------------------------------------
__global__ __launch_bounds__(256)
void transpose_v(const short* __restrict__ Vh, short* __restrict__ VT)
{
    const int lt = blockIdx.x;   // 0..31 (64-row L tile)
    const int bh = blockIdx.y;   // 0..23 (b*NH+h)
    const short* src = Vh + ((size_t)bh * Lq + lt * 64) * HDq;
    short* dst = VT + (size_t)bh * HDq * Lq + lt * 64;
    __shared__ __align__(16) short t[64][72];
    const int tid = threadIdx.x;
    {
        int row = tid & 63, seg = tid >> 6;          // seg: 16-col chunk
        *(short8*)&t[row][seg * 16]     = *(const short8*)&src[row * HDq + seg * 16];
        *(short8*)&t[row][seg * 16 + 8] = *(const short8*)&src[row * HDq + seg * 16 + 8];
    }
    __syncthreads();
    {
        int c = tid >> 2, seg = tid & 3;             // c: hd row, seg: 16-l chunk
        short8 o0, o1;
#pragma unroll
        for (int j = 0; j < 8; ++j) o0[j] = t[seg * 16 + j][c];
#pragma unroll
        for (int j = 0; j < 8; ++j) o1[j] = t[seg * 16 + 8 + j][c];
        *(short8*)&dst[(size_t)c * Lq + seg * 16]     = o0;
        *(short8*)&dst[(size_t)c * Lq + seg * 16 + 8] = o1;
    }
}

// ---------------------------------------------------------------------------
// MFMA flash attention, ZERO-LDS inner loop (attn was LDS-BW-bound: 104 KB
// LDS traffic/iter/block ~= measured 8.2K cy/iter -- see round-8 analysis).
//  - swapped QK^T: St = mfma32(A=K_from_global, B=Q_in_reg) -> St C-frag
//    [key=quad*4+reg][q=lane&15].
//  - St layout == B-frag layout of 16x16x16 MFMA (k=quad*4+j, col=lane&15):
//    P^T feeds PV directly from registers after in-lane f32->bf16 cvt.
//  - PV: O^T = mfma16(A=VT_from_global [d=lane&15][key=quad*4+j], B=P^T).
//  - 8 waves (512 thr): wave (qh=w>>2, kg=w&3) owns q-rows [qh*32,+32),
//    keys [kg*16,+16) of each 64-key tile. Un-normalized softmax is linear
//    in keys -> NO barriers / NO cross-wave work in the 32-iter loop;
//    one LDS O^T reduction (4 rounds) + l reduction in the epilogue.
//  - bias float4-vectorized (key is reg-consecutive now); K/V L2-resident
//    (XCD swizzle keeps b=0/1 siblings on one XCD).
// ---------------------------------------------------------------------------
__global__ __launch_bounds__(512, 4)
void attn_fwd_mfma(const short* __restrict__ Qh, const short* __restrict__ Kh,
                   const short* __restrict__ VT, const float* __restrict__ pos_bias,
                   const int* __restrict__ mask, short* __restrict__ AO)
{
    // hw block -> XCD chunk of 96 consecutive logicals; logical = (h*32+qt)*2+b
    const int hw = blockIdx.x;                     // 0..767
    const int logical = (hw & 7) * 96 + (hw >> 3);
    const int b  = logical & 1;
    const int qt = (logical >> 1) & 31;
    const int h  = logical >> 6;

    const short* Q = Qh + ((size_t)(b * NHq + h)) * Lq * HDq;
    const short* K = Kh + ((size_t)(b * NHq + h)) * Lq * HDq;
    const short* V = VT + ((size_t)(b * NHq + h)) * HDq * Lq;   // [hd][L]
    const int* mk = mask + (size_t)b * Lq;

    __shared__ float Ored[2][64][33];   // [qh][d][q] (+1 pad)
    __shared__ float lbuf[2][4][2][16]; // [qh][kg][mt][q]

    const int tid  = threadIdx.x;
    const int wave = tid >> 6;        // 0..7
    const int lane = tid & 63;
    const int col  = lane & 15;
    const int quad = lane >> 4;
    const int qh = wave >> 2;         // 0..1: q-half (32 rows)
    const int kg = wave & 3;          // 0..3: 16-key group

    // persistent Q B-frags [mt][kk]: col=q, k=kk*32+quad*8
    short8 qb[2][2];
#pragma unroll
    for (int mt = 0; mt < 2; ++mt) {
        const short* qrow = Q + (size_t)(qt * 64 + qh * 32 + mt * 16 + col) * HDq;
        qb[mt][0] = *(const short8*)&qrow[quad * 8];
        qb[mt][1] = *(const short8*)&qrow[32 + quad * 8];
    }

    // bias base: q = qt*64+qh*32+col (+ mt*16), key = kt*64 + kg*16 + quad*4 + j
    const float* bq = pos_bias + (size_t)h * Lq * Lq
                    + (size_t)(qt * 64 + qh * 32 + col) * Lq + kg * 16 + quad * 4;

    float4v bcur[2], bnxt[2];
    auto prefetch = [&](int kt, float4v (&bb)[2]) {
        int4v mv = *(const int4v*)&mk[kt * 64 + kg * 16 + quad * 4];
        float4v fm;
#pragma unroll
        for (int j = 0; j < 4; ++j) fm[j] = (mv[j] == 0) ? -1e30f : 0.0f;
#pragma unroll
        for (int mt = 0; mt < 2; ++mt) {
            float4v bv = *(const float4v*)(bq + (size_t)mt * 16 * Lq + kt * 64);
            bb[mt] = (bv + fm) * LOG2E;
        }
    };

    float4v Oacc[2][4];                // [mt][dblk]: O^T[d=dblk*16+quad*4+reg][q]
    float l_part[2] = {0.f, 0.f};
#pragma unroll
    for (int mt = 0; mt < 2; ++mt)
#pragma unroll
        for (int dblk = 0; dblk < 4; ++dblk) Oacc[mt][dblk] = (float4v){0.f, 0.f, 0.f, 0.f};

    prefetch(0, bcur);

    for (int kt = 0; kt < Lq / 64; ++kt) {
        if (kt + 1 < Lq / 64) prefetch(kt + 1, bnxt);

        // K A-frags: row=key(=kg*16+col of this tile), k=hd
        const short* krow = K + (size_t)(kt * 64 + kg * 16 + col) * HDq;
        short8 ka0 = *(const short8*)&krow[quad * 8];
        short8 ka1 = *(const short8*)&krow[32 + quad * 8];

        // --- swapped QK^T: St[mt] = K . Q^T  -> [key][q] ---
        float4v St[2] = {(float4v){0.f, 0.f, 0.f, 0.f}, (float4v){0.f, 0.f, 0.f, 0.f}};
        __builtin_amdgcn_s_setprio(1);
        St[0] = __builtin_amdgcn_mfma_f32_16x16x32_bf16(ka0, qb[0][0], St[0], 0, 0, 0);
        St[1] = __builtin_amdgcn_mfma_f32_16x16x32_bf16(ka0, qb[1][0], St[1], 0, 0, 0);
        St[0] = __builtin_amdgcn_mfma_f32_16x16x32_bf16(ka1, qb[0][1], St[0], 0, 0, 0);
        St[1] = __builtin_amdgcn_mfma_f32_16x16x32_bf16(ka1, qb[1][1], St[1], 0, 0, 0);
        __builtin_amdgcn_s_setprio(0);

        // --- no-max softmax in registers; P^T stays as 16x16x16 B-frag ---
        short4v pb[2];
#pragma unroll
        for (int mt = 0; mt < 2; ++mt) {
            float s0 = 0.f;
#pragma unroll
            for (int j = 0; j < 4; ++j) {
                float p = __builtin_amdgcn_exp2f(
                    __builtin_fmaf(St[mt][j], LOG2E, bcur[mt][j]));
                s0 += p;
                pb[mt][j] = f2bf(p);
            }
            l_part[mt] += s0;
        }

        // --- PV: O^T[d][q] += V^T[d][key] . P^T[key][q] ---
        __builtin_amdgcn_s_setprio(1);
#pragma unroll
        for (int dblk = 0; dblk < 4; ++dblk) {
            short4v va = *(const short4v*)
                &V[(size_t)(dblk * 16 + col) * Lq + kt * 64 + kg * 16 + quad * 4];
            Oacc[0][dblk] = mfma16(va, pb[0], Oacc[0][dblk]);
            Oacc[1][dblk] = mfma16(va, pb[1], Oacc[1][dblk]);
        }
        __builtin_amdgcn_s_setprio(0);

        bcur[0] = bnxt[0];
        bcur[1] = bnxt[1];
    }

    // --- epilogue: l reduce (quads then kg), O^T reduce over kg via LDS ---
#pragma unroll
    for (int mt = 0; mt < 2; ++mt) {
        float v = l_part[mt];
        v += __shfl_xor(v, 16, 64);
        v += __shfl_xor(v, 32, 64);
        l_part[mt] = v;                 // all lanes: sum over this wave's 16 keys
    }
    if (quad == 0) {
#pragma unroll
        for (int mt = 0; mt < 2; ++mt)
            lbuf[qh][kg][mt][col] = l_part[mt];
    }

    // 4-round O^T accumulate: kg==0 writes, kg==1..3 add
#pragma unroll
    for (int r = 0; r < 4; ++r) {
        if (r > 0) __syncthreads();
        if (kg == r) {
#pragma unroll
            for (int mt = 0; mt < 2; ++mt)
#pragma unroll
                for (int dblk = 0; dblk < 4; ++dblk)
#pragma unroll
                    for (int reg = 0; reg < 4; ++reg) {
                        int d = dblk * 16 + quad * 4 + reg;
                        int q = mt * 16 + col;
                        if (r == 0) Ored[qh][d][q]  = Oacc[mt][dblk][reg];
                        else        Ored[qh][d][q] += Oacc[mt][dblk][reg];
                    }
        }
    }
    __syncthreads();

    // --- normalize + store: thread -> (qh, q, 8-wide d chunk) ---
    {
        const int qh_t = tid >> 8;
        const int tt = tid & 255;
        const int q  = tt >> 3;            // 0..31
        const int d0 = (tt & 7) * 8;       // 0..56
        const int mtq = q >> 4, qc = q & 15;
        float l = lbuf[qh_t][0][mtq][qc] + lbuf[qh_t][1][mtq][qc]
                + lbuf[qh_t][2][mtq][qc] + lbuf[qh_t][3][mtq][qc];
        float inv = 1.0f / l;
        short8 o;
#pragma unroll
        for (int j = 0; j < 8; ++j)
            o[j] = f2bf(Ored[qh_t][d0 + j][q] * inv);
        *(short8*)&AO[((size_t)b * Lq + qt * 64 + qh_t * 32 + q) * DIMq
                      + h * HDq + d0] = o;
    }
}

// ---------------------------------------------------------------------------
extern "C" void kernel_launch(void* const* d_in, const int* in_sizes, int n_in,
                              void* d_out, int out_size, void* d_ws, size_t ws_size,
                              hipStream_t stream) {
    const float* x        = (const float*)d_in[0];
    const float* pos_bias = (const float*)d_in[1];
    const float* Wq       = (const float*)d_in[2];
    const float* Wk       = (const float*)d_in[3];
    const float* Wv       = (const float*)d_in[4];
    const float* Wo       = (const float*)d_in[5];
    const int*   mask     = (const int*)d_in[6];
    float* out = (float*)d_out;

    const size_t nX = (size_t)Bq * Lq * DIMq;       // 3,145,728
    const size_t nW = (size_t)DIMq * DIMq;          //   589,824
    short* xb  = (short*)d_ws;
    short* wqb = xb  + nX;
    short* wkb = wqb + nW;
    short* wvb = wkb + nW;
    short* wob = wvb + nW;
    short* Qh  = wob + nW;
    short* Kh  = Qh  + nX;
    short* Vh  = Kh  + nX;
    short* AOb = Vh  + nX;
    short* VTb = xb;   // xb is dead after the QKV GEMM; reuse for V^T

    dim3 blk(256);
    hipLaunchKernelGGL(to_bf16, dim3(1344), blk, 0, stream,
                       x, Wq, Wk, Wv, Wo, xb, wqb, wkb, wvb, wob);

    // fused QKV projections, 128x128 tiles, 3 blocks/CU single pass
    hipLaunchKernelGGL((gemm_bf16<128>), dim3(DIMq / 128, (Bq * Lq) / 128, 3), blk, 0, stream,
                       xb, wqb, wkb, wvb, Qh, Kh, Vh, (float*)nullptr, 1);

    // V: [B][NH][L][HD] -> [B][NH][HD][L]
    hipLaunchKernelGGL(transpose_v, dim3(Lq / 64, Bq * NHq), blk, 0, stream,
                       Vh, VTb);

    hipLaunchKernelGGL(attn_fwd_mfma, dim3(Lq / 64 * NHq * Bq), dim3(512), 0, stream,
                       Qh, Kh, VTb, pos_bias, mask, AOb);

    // output projection, 128x64 tiles -> 384 blocks (all CUs busy), fp32 out
    hipLaunchKernelGGL((gemm_bf16<64>), dim3(DIMq / 64, (Bq * Lq) / 128, 1), blk, 0, stream,
                       AOb, wob, wob, wob, (short*)nullptr, (short*)nullptr,
                       (short*)nullptr, out, 0);
}